// Round 9
// baseline (1267.687 us; speedup 1.0000x reference)
//
#include <hip/hip_runtime.h>
#include <hip/hip_bf16.h>
#include <math.h>

// Problem constants
#define BB 2
#define SS 2048
#define DD 1024
#define HH 16
#define DH 64

typedef __bf16 bf16;
typedef __bf16 bf16x8 __attribute__((ext_vector_type(8)));
typedef float f32x4 __attribute__((ext_vector_type(4)));

static const size_t NTOK  = (size_t)BB * SS * DD;   // 4,194,304
static const size_t STATN = (size_t)BB * HH * SS;   // 65,536

__device__ __forceinline__ f32x4 mfma16(bf16x8 a, bf16x8 b, f32x4 c) {
    return __builtin_amdgcn_mfma_f32_16x16x32_bf16(a, b, c, 0, 0, 0);
}

__device__ __forceinline__ bf16x8 cvt8(float4 a, float4 b) {
    bf16x8 r;
    r[0] = (bf16)a.x; r[1] = (bf16)a.y; r[2] = (bf16)a.z; r[3] = (bf16)a.w;
    r[4] = (bf16)b.x; r[5] = (bf16)b.y; r[6] = (bf16)b.z; r[7] = (bf16)b.w;
    return r;
}

template <typename AT>
__device__ __forceinline__ bf16x8 load_frag(const AT* p);
template <>
__device__ __forceinline__ bf16x8 load_frag<float>(const float* p) {
    float4 a = *(const float4*)p;
    float4 b = *(const float4*)(p + 4);
    return cvt8(a, b);
}
template <>
__device__ __forceinline__ bf16x8 load_frag<bf16>(const bf16* p) {
    return *(const bf16x8*)p;
}

// fp32 out: diagnostic signal (tripwire)
__global__ void signal_f(float* out, float v) {
    if (threadIdx.x == 0 && blockIdx.x == 0) out[0] = v;
}

// C[M,N] = A[M,K] @ W[N,K]^T + bias[N]   (torch Linear semantics)
// One wave per 16x16 C tile. MFMA 16x16x32 bf16, fp32 accumulate.
// AT: fp32 (harness inputs) or bf16 (ws ctx). CT: bf16 (staging) or fp32 (d_out).
template <typename AT, typename CT>
__global__ __launch_bounds__(256) void gemm_bias_bt(
    const AT* __restrict__ A, const float* __restrict__ W,
    const float* __restrict__ bias, CT* __restrict__ C,
    int M, int N, int K)
{
    int wave = blockIdx.x * (blockDim.x >> 6) + (threadIdx.x >> 6);
    int lane = threadIdx.x & 63;
    int tilesN = N >> 4;
    int tm = wave / tilesN;
    int tn = wave - tm * tilesN;
    if (tm >= (M >> 4)) return;
    int r16 = lane & 15;            // A row (m) for a-frag, W row (n) for b-frag
    int ko  = (lane >> 4) << 3;     // k offset within 32-slice

    const AT*    ap = A + (size_t)(tm * 16 + r16) * K + ko;
    const float* wp = W + (size_t)(tn * 16 + r16) * K + ko;
    f32x4 acc = {0.f, 0.f, 0.f, 0.f};
    for (int k = 0; k < K; k += 32) {
        bf16x8 af = load_frag<AT>(ap + k);
        bf16x8 wf = load_frag<float>(wp + k);
        acc = mfma16(af, wf, acc);
    }
    // D layout: col = lane&15 (n), row = quad*4+r (m)  [verified m89/m91]
    int n  = tn * 16 + r16;
    float bv = bias[n];
    int m0 = tm * 16 + ((lane >> 4) << 2);
    for (int r = 0; r < 4; ++r)
        C[(size_t)(m0 + r) * N + n] = (CT)(acc[r] + bv);
}

// Per-column (over q!) softmax stats: m_k = max_q s[q,k], Z_k = sum_q exp(s-m).
// One wave per (b,h, 16 k-columns). Online softmax along q; K-frags hoisted.
__global__ __launch_bounds__(64) void col_stats_kernel(
    const bf16* __restrict__ Q, const bf16* __restrict__ Km,
    float* __restrict__ mS, float* __restrict__ zS)
{
    int bid = blockIdx.x;
    int ktile = bid & (SS / 16 - 1);   // 0..127
    int bh    = bid >> 7;              // 0..31
    int b = bh >> 4, h = bh & (HH - 1);
    int lane = threadIdx.x & 63;
    int c16 = lane & 15;
    int ko  = (lane >> 4) << 3;

    const bf16* kp = Km + ((size_t)(b * SS + ktile * 16 + c16)) * DD + h * DH + ko;
    bf16x8 kf0 = *(const bf16x8*)(kp);
    bf16x8 kf1 = *(const bf16x8*)(kp + 32);
    const bf16* qbase = Q + ((size_t)(b * SS + c16)) * DD + h * DH + ko;

    float m = -INFINITY, z = 0.f;
    for (int q = 0; q < SS; q += 16) {
        const bf16* qp = qbase + (size_t)q * DD;
        bf16x8 qf0 = *(const bf16x8*)(qp);
        bf16x8 qf1 = *(const bf16x8*)(qp + 32);
        f32x4 acc = {0.f, 0.f, 0.f, 0.f};
        acc = mfma16(qf0, kf0, acc);
        acc = mfma16(qf1, kf1, acc);
        // D[q=quad*4+r][k=c16]; this lane's column is c16
        for (int r = 0; r < 4; ++r) {
            float s  = acc[r] * 0.125f;          // / sqrt(DH)=8
            float mn = fmaxf(m, s);
            z = z * __expf(m - mn) + __expf(s - mn);
            m = mn;
        }
    }
    // combine the 4 quads (lane bits 4,5) — each covered disjoint q rows
    for (int off = 16; off < 64; off <<= 1) {
        float mo = __shfl_xor(m, off, 64);
        float zo = __shfl_xor(z, off, 64);
        float mn = fmaxf(m, mo);
        z = z * __expf(m - mn) + zo * __expf(mo - mn);
        m = mn;
    }
    if (lane < 16) {
        size_t idx = (size_t)bh * SS + ktile * 16 + c16;
        mS[idx] = m;
        zS[idx] = z;
    }
}

// ctx[b, q, h*64+d] = sum_k exp(s[q,k]-m_k)/Z_k * V[k, h*64+d]
// One wave per (b,h, 16 q-rows). Recompute S tiles; P round-trips LDS
// (D-layout -> A-operand layout); V tile staged in LDS. Proper merge.
__global__ __launch_bounds__(64) void attn_ctx_kernel(
    const bf16* __restrict__ Q, const bf16* __restrict__ Km,
    const bf16* __restrict__ V, const float* __restrict__ mS,
    const float* __restrict__ zS, bf16* __restrict__ ctx)
{
    __shared__ bf16 Plds[16][32];
    __shared__ bf16 Vlds[32][DH];

    int bid = blockIdx.x;
    int qtile = bid & (SS / 16 - 1);
    int bh    = bid >> 7;
    int b = bh >> 4, h = bh & (HH - 1);
    int lane = threadIdx.x & 63;
    int c16  = lane & 15;
    int ko   = (lane >> 4) << 3;
    int quad = lane >> 4;

    const bf16* qp = Q + ((size_t)(b * SS + qtile * 16 + c16)) * DD + h * DH + ko;
    bf16x8 qf0 = *(const bf16x8*)(qp);
    bf16x8 qf1 = *(const bf16x8*)(qp + 32);

    f32x4 o[4] = {{0,0,0,0},{0,0,0,0},{0,0,0,0},{0,0,0,0}};
    const float* mrow = mS + (size_t)bh * SS;
    const float* zrow = zS + (size_t)bh * SS;

    for (int kb = 0; kb < SS; kb += 32) {
        // --- compute P tile: 16(q) x 32(k), normalize by COLUMN stats ---
        for (int t = 0; t < 2; ++t) {
            const bf16* kp = Km + ((size_t)(b * SS + kb + t * 16 + c16)) * DD + h * DH + ko;
            bf16x8 kf0 = *(const bf16x8*)(kp);
            bf16x8 kf1 = *(const bf16x8*)(kp + 32);
            f32x4 acc = {0.f, 0.f, 0.f, 0.f};
            acc = mfma16(qf0, kf0, acc);
            acc = mfma16(qf1, kf1, acc);
            int kg = kb + t * 16 + c16;
            float mk = mrow[kg];
            float rz = 1.0f / zrow[kg];
            for (int r = 0; r < 4; ++r) {
                float p = __expf(acc[r] * 0.125f - mk) * rz;
                Plds[quad * 4 + r][t * 16 + c16] = (bf16)p;
            }
        }
        // --- stage V tile 32 x 64 ---
        for (int i = 0; i < 4; ++i) {
            int chunk = i * 64 + lane;   // 256 chunks of 8 bf16
            int vr = chunk >> 3;
            int vc = (chunk & 7) << 3;
            *(bf16x8*)&Vlds[vr][vc] =
                *(const bf16x8*)(V + ((size_t)(b * SS + kb + vr)) * DD + h * DH + vc);
        }
        __syncthreads();
        // P in A-operand layout: contiguous 8 from row (lane&15)
        bf16x8 pf = *(const bf16x8*)&Plds[c16][ko];
        for (int dt = 0; dt < 4; ++dt) {
            bf16x8 vf;
            for (int j = 0; j < 8; ++j) vf[j] = Vlds[ko + j][dt * 16 + c16];
            o[dt] = mfma16(pf, vf, o[dt]);
        }
        __syncthreads();
    }
    for (int dt = 0; dt < 4; ++dt)
        for (int r = 0; r < 4; ++r)
            ctx[((size_t)(b * SS + qtile * 16 + quad * 4 + r)) * DD + h * DH + dt * 16 + c16] =
                (bf16)(o[dt][r]);
}

extern "C" void kernel_launch(void* const* d_in, const int* in_sizes, int n_in,
                              void* d_out, int out_size, void* d_ws, size_t ws_size,
                              hipStream_t stream) {
    const float* query = (const float*)d_in[0];
    const float* key   = (const float*)d_in[1];
    const float* value = (const float*)d_in[2];
    const float* Wq = (const float*)d_in[3];
    const float* bq = (const float*)d_in[4];
    const float* Wk = (const float*)d_in[5];
    const float* bk = (const float*)d_in[6];
    const float* Wv = (const float*)d_in[7];
    const float* bv = (const float*)d_in[8];
    const float* Wo = (const float*)d_in[9];
    const float* bo = (const float*)d_in[10];
    float* out = (float*)d_out;   // fp32 output — confirmed by R8 probe

    // tripwire: verify assumed input layout
    if (n_in != 11 || in_sizes[0] != (int)NTOK || in_sizes[3] != DD * DD ||
        in_sizes[4] != DD || out_size != (int)NTOK) {
        hipLaunchKernelGGL(signal_f, dim3(1), dim3(64), 0, stream, out, -64.0f);
        return;
    }

    // bf16 staging workspace: 4*8 MiB + stats (ws >= 34.1 MB confirmed R2-R7)
    bf16* Qs  = (bf16*)d_ws;
    bf16* Ks  = Qs + NTOK;
    bf16* Vs  = Ks + NTOK;
    bf16* Cs  = Vs + NTOK;
    float* mS = (float*)(Cs + NTOK);
    float* zS = mS + STATN;

    const int M = BB * SS, N = DD, K = DD;
    dim3 gb(4096), gt(256);                     // 4 waves/block, 1 tile/wave
    hipLaunchKernelGGL((gemm_bias_bt<float, bf16>), gb, gt, 0, stream, query, Wq, bq, Qs, M, N, K);
    hipLaunchKernelGGL((gemm_bias_bt<float, bf16>), gb, gt, 0, stream, key,   Wk, bk, Ks, M, N, K);
    hipLaunchKernelGGL((gemm_bias_bt<float, bf16>), gb, gt, 0, stream, value, Wv, bv, Vs, M, N, K);

    dim3 ab(BB * HH * SS / 16), at(64);         // 4096 single-wave blocks
    hipLaunchKernelGGL(col_stats_kernel, ab, at, 0, stream, Qs, Ks, mS, zS);
    hipLaunchKernelGGL(attn_ctx_kernel,  ab, at, 0, stream, Qs, Ks, Vs, mS, zS, Cs);

    hipLaunchKernelGGL((gemm_bias_bt<bf16, float>), gb, gt, 0, stream, Cs, Wo, bo, out, M, N, K);
}

// Round 10
// 568.635 us; speedup vs baseline: 2.2293x; 2.2293x over previous
//
#include <hip/hip_runtime.h>
#include <hip/hip_bf16.h>
#include <math.h>

// Problem constants
#define BB 2
#define SS 2048
#define DD 1024
#define HH 16
#define DH 64

typedef __bf16 bf16;
typedef __bf16 bf16x8 __attribute__((ext_vector_type(8)));
typedef float f32x4 __attribute__((ext_vector_type(4)));

static const size_t NTOK  = (size_t)BB * SS * DD;   // 4,194,304
static const size_t STATN = (size_t)BB * HH * SS;   // 65,536

__device__ __forceinline__ f32x4 mfma16(bf16x8 a, bf16x8 b, f32x4 c) {
    return __builtin_amdgcn_mfma_f32_16x16x32_bf16(a, b, c, 0, 0, 0);
}

__device__ __forceinline__ bf16x8 cvt8(float4 a, float4 b) {
    bf16x8 r;
    r[0] = (bf16)a.x; r[1] = (bf16)a.y; r[2] = (bf16)a.z; r[3] = (bf16)a.w;
    r[4] = (bf16)b.x; r[5] = (bf16)b.y; r[6] = (bf16)b.z; r[7] = (bf16)b.w;
    return r;
}

// load 8 elements as bf16x8 from fp32 or bf16 source
template <typename AT>
__device__ __forceinline__ bf16x8 load8(const AT* p);
template <>
__device__ __forceinline__ bf16x8 load8<float>(const float* p) {
    float4 a = *(const float4*)p;
    float4 b = *(const float4*)(p + 4);
    return cvt8(a, b);
}
template <>
__device__ __forceinline__ bf16x8 load8<bf16>(const bf16* p) {
    return *(const bf16x8*)p;
}

__global__ void signal_f(float* out, float v) {
    if (threadIdx.x == 0 && blockIdx.x == 0) out[0] = v;
}

// ---------------------------------------------------------------------------
// Tiled GEMM: C[M,N] = A[M,K] @ W[N,K]^T + bias[N]   (torch Linear)
// Block: 256 thr / 4 waves; tile 128(M) x 64(N); BK=32.
// Waves 2x2; each wave 64x32 = 4x2 MFMA 16x16x32 tiles.
// fp32->bf16 conversion fused into LDS staging. LDS rows padded to 40 bf16
// (80 B: 16B-aligned for b128, 2-way bank aliasing = free).
// M=4096, N=1024, K=1024 fixed shape (asserted by tripwire).
// ---------------------------------------------------------------------------
#define Bb 128
#define BN 64
#define BKt 32
#define LDP 40

template <typename AT, typename CT>
__global__ __launch_bounds__(256) void gemm_tile(
    const AT* __restrict__ A, const float* __restrict__ W,
    const float* __restrict__ bias, CT* __restrict__ C,
    int M, int N, int K)
{
    __shared__ bf16 As[Bb][LDP];
    __shared__ bf16 Bs[BN][LDP];

    int t = (int)threadIdx.x;
    int tilesN = N / BN;
    int tm = blockIdx.x / tilesN;
    int tn = blockIdx.x % tilesN;

    int lane = t & 63;
    int w    = t >> 6;
    int wm   = w >> 1, wn = w & 1;       // 2x2 wave grid
    int c16  = lane & 15;
    int quad = lane >> 4;
    int ko   = quad << 3;

    // staging coords
    int arow = t >> 1, acb = (t & 1) * 16;   // A: 128 rows x 32, 16 elem/thread
    int brow = t >> 2, bcb = (t & 3) * 8;    // B: 64 rows x 32,  8 elem/thread

    const AT*    abase = A + (size_t)(tm * Bb + arow) * K + acb;
    const float* wbase = W + (size_t)(tn * BN + brow) * K + bcb;

    f32x4 acc[4][2];
#pragma unroll
    for (int i = 0; i < 4; ++i)
#pragma unroll
        for (int j = 0; j < 2; ++j) acc[i][j] = (f32x4){0.f, 0.f, 0.f, 0.f};

    for (int k0 = 0; k0 < K; k0 += BKt) {
        // stage A (fp32->bf16 or bf16 copy)
        bf16x8 a0 = load8<AT>(abase + k0);
        bf16x8 a1 = load8<AT>(abase + k0 + 8);
        bf16x8 b0 = load8<float>(wbase + k0);
        *(bf16x8*)&As[arow][acb]     = a0;
        *(bf16x8*)&As[arow][acb + 8] = a1;
        *(bf16x8*)&Bs[brow][bcb]     = b0;
        __syncthreads();

        bf16x8 af[4], bf[2];
#pragma unroll
        for (int mt = 0; mt < 4; ++mt)
            af[mt] = *(const bf16x8*)&As[wm * 64 + mt * 16 + c16][ko];
#pragma unroll
        for (int nt = 0; nt < 2; ++nt)
            bf[nt] = *(const bf16x8*)&Bs[wn * 32 + nt * 16 + c16][ko];
#pragma unroll
        for (int mt = 0; mt < 4; ++mt)
#pragma unroll
            for (int nt = 0; nt < 2; ++nt)
                acc[mt][nt] = mfma16(af[mt], bf[nt], acc[mt][nt]);
        __syncthreads();
    }

    // epilogue: D col = lane&15 (n), row = quad*4+r (m)  [verified m89/m91]
#pragma unroll
    for (int nt = 0; nt < 2; ++nt) {
        int col = tn * BN + wn * 32 + nt * 16 + c16;
        float bv = bias[col];
#pragma unroll
        for (int mt = 0; mt < 4; ++mt) {
            int r0 = tm * Bb + wm * 64 + mt * 16 + quad * 4;
#pragma unroll
            for (int r = 0; r < 4; ++r)
                C[(size_t)(r0 + r) * N + col] = (CT)(acc[mt][nt][r] + bv);
        }
    }
}

// ---------------------------------------------------------------------------
// Per-column (over q!) softmax stats: m_k = max_q s[q,k], Z_k = sum_q exp(s-m)
// ---------------------------------------------------------------------------
__global__ __launch_bounds__(64) void col_stats_kernel(
    const bf16* __restrict__ Q, const bf16* __restrict__ Km,
    float* __restrict__ mS, float* __restrict__ zS)
{
    int bid = blockIdx.x;
    int ktile = bid & (SS / 16 - 1);   // 0..127
    int bh    = bid >> 7;              // 0..31
    int b = bh >> 4, h = bh & (HH - 1);
    int lane = threadIdx.x & 63;
    int c16 = lane & 15;
    int ko  = (lane >> 4) << 3;

    const bf16* kp = Km + ((size_t)(b * SS + ktile * 16 + c16)) * DD + h * DH + ko;
    bf16x8 kf0 = *(const bf16x8*)(kp);
    bf16x8 kf1 = *(const bf16x8*)(kp + 32);
    const bf16* qbase = Q + ((size_t)(b * SS + c16)) * DD + h * DH + ko;

    float m = -INFINITY, z = 0.f;
    for (int q = 0; q < SS; q += 16) {
        const bf16* qp = qbase + (size_t)q * DD;
        bf16x8 qf0 = *(const bf16x8*)(qp);
        bf16x8 qf1 = *(const bf16x8*)(qp + 32);
        f32x4 acc = {0.f, 0.f, 0.f, 0.f};
        acc = mfma16(qf0, kf0, acc);
        acc = mfma16(qf1, kf1, acc);
        for (int r = 0; r < 4; ++r) {
            float s  = acc[r] * 0.125f;          // / sqrt(DH)=8
            float mn = fmaxf(m, s);
            z = z * __expf(m - mn) + __expf(s - mn);
            m = mn;
        }
    }
    for (int off = 16; off < 64; off <<= 1) {
        float mo = __shfl_xor(m, off, 64);
        float zo = __shfl_xor(z, off, 64);
        float mn = fmaxf(m, mo);
        z = z * __expf(m - mn) + zo * __expf(mo - mn);
        m = mn;
    }
    if (lane < 16) {
        size_t idx = (size_t)bh * SS + ktile * 16 + c16;
        mS[idx] = m;
        zS[idx] = z;
    }
}

// ---------------------------------------------------------------------------
// ctx[b, q, h*64+d] = sum_k exp(s[q,k]-m_k)/Z_k * V[k, h*64+d]
// ---------------------------------------------------------------------------
__global__ __launch_bounds__(64) void attn_ctx_kernel(
    const bf16* __restrict__ Q, const bf16* __restrict__ Km,
    const bf16* __restrict__ V, const float* __restrict__ mS,
    const float* __restrict__ zS, bf16* __restrict__ ctx)
{
    __shared__ bf16 Plds[16][32];
    __shared__ bf16 Vlds[32][DH];

    int bid = blockIdx.x;
    int qtile = bid & (SS / 16 - 1);
    int bh    = bid >> 7;
    int b = bh >> 4, h = bh & (HH - 1);
    int lane = threadIdx.x & 63;
    int c16  = lane & 15;
    int ko   = (lane >> 4) << 3;
    int quad = lane >> 4;

    const bf16* qp = Q + ((size_t)(b * SS + qtile * 16 + c16)) * DD + h * DH + ko;
    bf16x8 qf0 = *(const bf16x8*)(qp);
    bf16x8 qf1 = *(const bf16x8*)(qp + 32);

    f32x4 o[4] = {{0,0,0,0},{0,0,0,0},{0,0,0,0},{0,0,0,0}};
    const float* mrow = mS + (size_t)bh * SS;
    const float* zrow = zS + (size_t)bh * SS;

    for (int kb = 0; kb < SS; kb += 32) {
        for (int t = 0; t < 2; ++t) {
            const bf16* kp = Km + ((size_t)(b * SS + kb + t * 16 + c16)) * DD + h * DH + ko;
            bf16x8 kf0 = *(const bf16x8*)(kp);
            bf16x8 kf1 = *(const bf16x8*)(kp + 32);
            f32x4 acc = {0.f, 0.f, 0.f, 0.f};
            acc = mfma16(qf0, kf0, acc);
            acc = mfma16(qf1, kf1, acc);
            int kg = kb + t * 16 + c16;
            float mk = mrow[kg];
            float rz = 1.0f / zrow[kg];
            for (int r = 0; r < 4; ++r) {
                float p = __expf(acc[r] * 0.125f - mk) * rz;
                Plds[quad * 4 + r][t * 16 + c16] = (bf16)p;
            }
        }
        for (int i = 0; i < 4; ++i) {
            int chunk = i * 64 + lane;   // 256 chunks of 8 bf16
            int vr = chunk >> 3;
            int vc = (chunk & 7) << 3;
            *(bf16x8*)&Vlds[vr][vc] =
                *(const bf16x8*)(V + ((size_t)(b * SS + kb + vr)) * DD + h * DH + vc);
        }
        __syncthreads();
        bf16x8 pf = *(const bf16x8*)&Plds[c16][ko];
        for (int dt = 0; dt < 4; ++dt) {
            bf16x8 vf;
            for (int j = 0; j < 8; ++j) vf[j] = Vlds[ko + j][dt * 16 + c16];
            o[dt] = mfma16(pf, vf, o[dt]);
        }
        __syncthreads();
    }
    for (int dt = 0; dt < 4; ++dt)
        for (int r = 0; r < 4; ++r)
            ctx[((size_t)(b * SS + qtile * 16 + quad * 4 + r)) * DD + h * DH + dt * 16 + c16] =
                (bf16)(o[dt][r]);
}

extern "C" void kernel_launch(void* const* d_in, const int* in_sizes, int n_in,
                              void* d_out, int out_size, void* d_ws, size_t ws_size,
                              hipStream_t stream) {
    const float* query = (const float*)d_in[0];
    const float* key   = (const float*)d_in[1];
    const float* value = (const float*)d_in[2];
    const float* Wq = (const float*)d_in[3];
    const float* bq = (const float*)d_in[4];
    const float* Wk = (const float*)d_in[5];
    const float* bk = (const float*)d_in[6];
    const float* Wv = (const float*)d_in[7];
    const float* bv = (const float*)d_in[8];
    const float* Wo = (const float*)d_in[9];
    const float* bo = (const float*)d_in[10];
    float* out = (float*)d_out;   // fp32 output — confirmed by R8 probe

    if (n_in != 11 || in_sizes[0] != (int)NTOK || in_sizes[3] != DD * DD ||
        in_sizes[4] != DD || out_size != (int)NTOK) {
        hipLaunchKernelGGL(signal_f, dim3(1), dim3(64), 0, stream, out, -64.0f);
        return;
    }

    // bf16 staging workspace (ws in [34.1, 67.6) MB per R2-R7 evidence)
    bf16* Qs  = (bf16*)d_ws;
    bf16* Ks  = Qs + NTOK;
    bf16* Vs  = Ks + NTOK;
    bf16* Cs  = Vs + NTOK;
    float* mS = (float*)(Cs + NTOK);
    float* zS = mS + STATN;

    const int M = BB * SS, N = DD, K = DD;
    dim3 gb((M / Bb) * (N / BN)), gt(256);      // 32*16 = 512 blocks, 2/CU
    hipLaunchKernelGGL((gemm_tile<float, bf16>), gb, gt, 0, stream, query, Wq, bq, Qs, M, N, K);
    hipLaunchKernelGGL((gemm_tile<float, bf16>), gb, gt, 0, stream, key,   Wk, bk, Ks, M, N, K);
    hipLaunchKernelGGL((gemm_tile<float, bf16>), gb, gt, 0, stream, value, Wv, bv, Vs, M, N, K);

    dim3 ab(BB * HH * SS / 16), at(64);         // 4096 single-wave blocks
    hipLaunchKernelGGL(col_stats_kernel, ab, at, 0, stream, Qs, Ks, mS, zS);
    hipLaunchKernelGGL(attn_ctx_kernel,  ab, at, 0, stream, Qs, Ks, Vs, mS, zS, Cs);

    hipLaunchKernelGGL((gemm_tile<bf16, float>), gb, gt, 0, stream, Cs, Wo, bo, out, M, N, K);
}